// Round 6
// baseline (391.085 us; speedup 1.0000x reference)
//
#include <hip/hip_runtime.h>
#include <hip/hip_fp16.h>
#include <math.h>

#define D 128
#define SH 9               // fine bucket shift: 512 dsts per bucket
#define BW (1 << SH)
#define EPT 16             // edges per thread in binning kernels

typedef _Float16 half4v __attribute__((ext_vector_type(4)));
typedef _Float16 half8  __attribute__((ext_vector_type(8)));
typedef float    floatx16 __attribute__((ext_vector_type(16)));

typedef __attribute__((address_space(3))) uint32_t lds_u32_t;
typedef const __attribute__((address_space(1))) uint32_t g_u32_t;

// ---------------------------------------------------------------------------
// Cast fp32 -> fp16 (4 elems/thread).
// ---------------------------------------------------------------------------
__global__ __launch_bounds__(256) void cast_half(
        const float* __restrict__ x, _Float16* __restrict__ y, int n) {
    int i = blockIdx.x * 256 + threadIdx.x;
    int idx = i * 4;
    if (idx >= n) return;
    float4 v = *(const float4*)(x + idx);
    half4v h;
    h[0] = (_Float16)v.x; h[1] = (_Float16)v.y;
    h[2] = (_Float16)v.z; h[3] = (_Float16)v.w;
    *(half4v*)(y + idx) = h;
}

// ---------------------------------------------------------------------------
// Build B fragments pre-swizzled for v_mfma_f32_32x32x16_f16, BOTH layers
// in one launch. WT[k][c] = (k<128) ? w_l[c][k] : w_r[c][k-128].
// Fragment f = ks*4+cb, lane l, elem j:
//   value = WT[ks*16 + (l>>5)*8 + j][cb*32 + (l&31)] at B[f*512 + l*8 + j].
// ---------------------------------------------------------------------------
__global__ __launch_bounds__(256) void prep_bswz2(
        const float* __restrict__ wl0, const float* __restrict__ wr0,
        const float* __restrict__ wl1, const float* __restrict__ wr1,
        _Float16* __restrict__ B0, _Float16* __restrict__ B1) {
    int gid = blockIdx.x * 256 + threadIdx.x;   // 2 * 32768
    if (gid >= 2 * 64 * 512) return;
    int layer = gid >> 15;
    int idx = gid & 32767;
    const float* wl = layer ? wl1 : wl0;
    const float* wr = layer ? wr1 : wr0;
    _Float16* B = layer ? B1 : B0;
    int j = idx & 7;
    int lane = (idx >> 3) & 63;
    int f = idx >> 9;
    int ks = f >> 2, cb = f & 3;
    int k = ks * 16 + (lane >> 5) * 8 + j;
    int c = cb * 32 + (lane & 31);
    float v = (k < 128) ? wl[c * 128 + k] : wr[c * 128 + (k - 128)];
    B[idx] = (_Float16)v;
}

// ---------------------------------------------------------------------------
// Coarse histogram: per (graph, fine-bucket) edge counts. LDS hist per block,
// one global atomic per nonzero bin per block (line-padded ccnt[b*16]).
// ---------------------------------------------------------------------------
__global__ __launch_bounds__(256) void hist_coarse(
        const int* __restrict__ ei0, const int* __restrict__ ei1,
        int E, int NBK, int* __restrict__ ccnt) {
    __shared__ int h[512];
    int NBIN = 2 * NBK;
    int t = threadIdx.x;
    h[t] = 0; h[t + 256] = 0;
    __syncthreads();
    int t0 = blockIdx.x * (256 * EPT) + t;
#pragma unroll
    for (int k = 0; k < EPT; ++k) {
        int idx = t0 + k * 256;
        if (idx < 2 * E) {
            int g = idx >= E;
            int e = idx - g * E;
            int dst = (g ? ei1 : ei0)[E + e];
            atomicAdd(&h[g * NBK + (dst >> SH)], 1);
        }
    }
    __syncthreads();
    for (int b = t; b < NBIN; b += 256)
        if (h[b]) atomicAdd(&ccnt[b * 16], h[b]);
}

// ---------------------------------------------------------------------------
// Coarse scan: one block; per-graph exclusive prefix over NBK bin counts.
// Writes gbase[b] (bucket start in stage/es space) and inits gcur[b*16].
// Also writes rp0[N]=rp1[N]=E.
// ---------------------------------------------------------------------------
__global__ __launch_bounds__(256) void scan_coarse(
        const int* __restrict__ ccnt, int NBK, int E, int N,
        int* __restrict__ gbase, int* __restrict__ gcur,
        int* __restrict__ rp0, int* __restrict__ rp1) {
    __shared__ int part[256];
    int t = threadIdx.x;
    for (int g = 0; g < 2; ++g) {
        int v = (t < NBK) ? ccnt[(g * NBK + t) * 16] : 0;
        part[t] = v;
        __syncthreads();
        for (int off = 1; off < 256; off <<= 1) {
            int u = (t >= off) ? part[t - off] : 0;
            __syncthreads();
            part[t] += u;
            __syncthreads();
        }
        if (t < NBK) {
            int ex = (t == 0) ? 0 : part[t - 1];
            int b = g * NBK + t;
            gbase[b] = ex;
            gcur[b * 16] = ex;
        }
        __syncthreads();
    }
    if (t == 0) { rp0[N] = E; rp1[N] = E; }
}

// ---------------------------------------------------------------------------
// Multisplit pass 1: bin edges into fine buckets. 4096 edges/block.
// LDS histogram -> one global reserve atomic per (block,bin) -> LDS-rank
// scatter of packed (src | dstlow<<17) into the per-graph stage array.
// ---------------------------------------------------------------------------
__global__ __launch_bounds__(256) void bin_pass1(
        const int* __restrict__ ei0, const int* __restrict__ ei1,
        int E, int NBK, int* __restrict__ gcur,
        int* __restrict__ stage0, int* __restrict__ stage1) {
    __shared__ int cnt[512];
    __shared__ int base[512];
    int NBIN = 2 * NBK;
    int t = threadIdx.x;
    cnt[t] = 0; cnt[t + 256] = 0;
    __syncthreads();
    int t0 = blockIdx.x * (256 * EPT) + t;
    int pk[EPT];
    int bn[EPT];
#pragma unroll
    for (int k = 0; k < EPT; ++k) {
        int idx = t0 + k * 256;
        bn[k] = -1;
        if (idx < 2 * E) {
            int g = idx >= E;
            int e = idx - g * E;
            const int* ei = g ? ei1 : ei0;
            int src = ei[e];
            int dst = ei[E + e];
            pk[k] = src | ((dst & (BW - 1)) << 17);
            bn[k] = g * NBK + (dst >> SH);
            atomicAdd(&cnt[bn[k]], 1);
        }
    }
    __syncthreads();
    for (int b = t; b < NBIN; b += 256) {
        int c = cnt[b];
        base[b] = c ? atomicAdd(&gcur[b * 16], c) : 0;
        cnt[b] = 0;  // reuse as rank counter
    }
    __syncthreads();
#pragma unroll
    for (int k = 0; k < EPT; ++k) {
        if (bn[k] >= 0) {
            int b = bn[k];
            int r = atomicAdd(&cnt[b], 1);
            int* stage = (b >= NBK) ? stage1 : stage0;
            stage[base[b] + r] = pk[k];
        }
    }
}

// ---------------------------------------------------------------------------
// Multisplit pass 2: one block per fine bucket (2*NBK blocks).
// Counts its 512 dsts in LDS, in-block scan -> writes row_ptr slice and LDS
// cursors, then scatters srcs into final CSR slots. All es writes for this
// ~32 KB region come from ONE block -> L2 merges to full lines.
// ---------------------------------------------------------------------------
__global__ __launch_bounds__(256) void bin_pass2(
        const int* __restrict__ gbase,
        const int* __restrict__ stage0, const int* __restrict__ stage1,
        int* __restrict__ rp0, int* __restrict__ rp1,
        int* __restrict__ es0, int* __restrict__ es1,
        int N, int NBK, int E) {
    __shared__ int cnt[BW];
    __shared__ int part[256];
    int b = blockIdx.x;
    int g = b >= NBK;
    int bk = b - g * NBK;
    const int* stage = g ? stage1 : stage0;
    int* rp = g ? rp1 : rp0;
    int* es = g ? es1 : es0;
    int lo = bk << SH;
    int hi = min(lo + BW, N);
    int nd = hi - lo;
    int beg = gbase[b];
    int end = (bk == NBK - 1) ? E : gbase[b + 1];
    int t = threadIdx.x;
    cnt[t] = 0; cnt[t + 256] = 0;
    __syncthreads();
    for (int i = beg + t; i < end; i += 256)
        atomicAdd(&cnt[(unsigned)stage[i] >> 17], 1);
    __syncthreads();
    int c0 = cnt[t * 2], c1 = cnt[t * 2 + 1];
    part[t] = c0 + c1;
    __syncthreads();
    for (int off = 1; off < 256; off <<= 1) {
        int u = (t >= off) ? part[t - off] : 0;
        __syncthreads();
        part[t] += u;
        __syncthreads();
    }
    int ex = (t == 0) ? 0 : part[t - 1];
    int base0 = beg + ex;
    if (t * 2 < nd)     rp[lo + t * 2]     = base0;
    if (t * 2 + 1 < nd) rp[lo + t * 2 + 1] = base0 + c0;
    __syncthreads();               // all reads of cnt done (scan barriers passed)
    cnt[t * 2] = base0;
    cnt[t * 2 + 1] = base0 + c0;
    __syncthreads();
    int i = beg + t;
    for (; i + 768 < end; i += 1024) {
        unsigned p0 = (unsigned)stage[i];
        unsigned p1 = (unsigned)stage[i + 256];
        unsigned p2 = (unsigned)stage[i + 512];
        unsigned p3 = (unsigned)stage[i + 768];
        int q0 = atomicAdd(&cnt[p0 >> 17], 1);
        int q1 = atomicAdd(&cnt[p1 >> 17], 1);
        int q2 = atomicAdd(&cnt[p2 >> 17], 1);
        int q3 = atomicAdd(&cnt[p3 >> 17], 1);
        es[q0] = p0 & 0x1FFFF;
        es[q1] = p1 & 0x1FFFF;
        es[q2] = p2 & 0x1FFFF;
        es[q3] = p3 & 0x1FFFF;
    }
    for (; i < end; i += 256) {
        unsigned p = (unsigned)stage[i];
        int q = atomicAdd(&cnt[p >> 17], 1);
        es[q] = p & 0x1FFFF;
    }
}

// ---------------------------------------------------------------------------
// Fast exact-GELU: erf via Abramowitz-Stegun 7.1.26 (|eps| <= 1.5e-7).
// ---------------------------------------------------------------------------
__device__ __forceinline__ float gelu_fast(float v) {
    float z = v * 0.70710678118654752f;
    float s = fabsf(z);
    float t = __builtin_amdgcn_rcpf(fmaf(0.3275911f, s, 1.0f));
    float poly = t * fmaf(t, fmaf(t, fmaf(t, fmaf(t, 1.061405429f,
                      -1.453152027f), 1.421413741f), -0.284496736f),
                      0.254829592f);
    float e = __builtin_amdgcn_exp2f(-1.4426950408889634f * s * s);
    float erfv = copysignf(fmaf(-poly, e, 1.0f), z);
    return 0.5f * v * (1.0f + erfv);
}

// ---------------------------------------------------------------------------
// FUSED gather-mean + SAGE linear, v6 (round 10).
// R5 profile: agg (gather) 56.5 us with MFMA idle; sage ~50 us with every
// pipe idle; 51 MB/layer agg_h round-trip exists only to connect them.
// Fusion: per 64-node block,
//   1. issue x-row staging (global_load_lds, chunks 16..31) + B-frag loads
//      (pinned, 16 frags = 64 VGPR; waves split 1x4 over column blocks)
//   2. gather-mean for nodes n0..n0+63 directly into LDS chunks 0..15
//      (same half4 rounding as old agg_half -> bitwise-identical result)
//   3. one barrier, pure LDS+MFMA (32 MFMAs/wave), epilogue.
// B/x latency hides under gather; resident blocks' MFMA overlaps gather
// latency; agg_h traffic and 2 dispatches eliminated.
// ---------------------------------------------------------------------------
template <bool GELU, typename OutT>
__global__ __launch_bounds__(256, 3) void fused_sage(
        const _Float16* __restrict__ xsrc, const int* __restrict__ rp,
        const int* __restrict__ es, const _Float16* __restrict__ Bswz,
        const float* __restrict__ bias, OutT* __restrict__ out, int N) {
    __shared__ uint4 a_lds[32 * 65];   // 33280 B: 32 chunks of 4 rows + 16B pad

    const int tid = threadIdx.x;
    const int n0 = blockIdx.x * 64;
    const int wave = tid >> 6;
    const int lane = tid & 63;
    const int l31 = lane & 31;
    const int lhi = lane >> 5;

    // ---- 1a. x-row staging: chunks 16..31 hold x rows n0..n0+63 ----
    if (n0 + 64 <= N) {
#pragma unroll
        for (int i = 0; i < 4; ++i) {
            int c = 16 + wave * 4 + i;
            int r0 = n0 + 4 * (c & 15);
            const char* g = (const char*)xsrc + (size_t)r0 * 256 + lane * 16;
            uint32_t* l = (uint32_t*)((char*)a_lds + c * 1040);
            __builtin_amdgcn_global_load_lds((g_u32_t*)g, (lds_u32_t*)l,
                                             16, 0, 0);
        }
    } else {
#pragma unroll
        for (int i = 0; i < 4; ++i) {
            int c = 16 + wave * 4 + i;
            int grow = n0 + 4 * (c & 15) + (lane >> 4);
            uint4 v = make_uint4(0u, 0u, 0u, 0u);
            if (grow < N)
                v = *(const uint4*)((const char*)xsrc + (size_t)grow * 256
                                    + (lane & 15) * 16);
            *(uint4*)((char*)a_lds + c * 1040 + lane * 16) = v;
        }
    }

    // ---- 1b. B fragments for col-block cb = wave, pinned live ----
    half8 breg[2][8];
#pragma unroll
    for (int ph = 0; ph < 2; ++ph)
#pragma unroll
        for (int ks = 0; ks < 8; ++ks)
            breg[ph][ks] = *(const half8*)(
                Bswz + (size_t)ph * 16384 + ((ks * 4) + wave) * 512 + lane * 8);
#pragma unroll
    for (int ph = 0; ph < 2; ++ph)
#pragma unroll
        for (int ks = 0; ks < 8; ++ks)
            asm volatile("" : "+v"(breg[ph][ks]));

    // ---- 2. gather-mean: wave handles dst nodes n0+wave*16 .. +15 ----
    {
        int nb = n0 + wave * 16;
        int rpi = min(nb + lane, N);
        int rpv = (lane < 17) ? rp[rpi] : 0;
        const char* xb = (const char*)xsrc;
        int grp = lane >> 5;               // which edge of the pair
        unsigned co = (unsigned)l31 * 8u;  // byte offset within 256 B row
        float one = 1.0f;
        for (int k = 0; k < 16; ++k) {
            int beg = __shfl(rpv, k);
            int end = __shfl(rpv, k + 1);
            float ax = 0.f, ay = 0.f, az = 0.f, aw = 0.f;
            for (int chunk = beg; chunk < end; chunk += 64) {
                int n = min(64, end - chunk);
                int iv = (lane < n) ? es[chunk + lane] : -1;
                for (int e = 0; e < n; e += 8) {
                    int s[4];
                    uint2 v[4];
#pragma unroll
                    for (int j = 0; j < 4; ++j)
                        s[j] = __shfl(iv, e + 2 * j + grp);   // -1 past end
#pragma unroll
                    for (int j = 0; j < 4; ++j) {
                        v[j] = make_uint2(0u, 0u);
                        if (s[j] >= 0)
                            v[j] = *(const uint2*)(xb + (unsigned)s[j] * 256u
                                                   + co);
                    }
#pragma unroll
                    for (int j = 0; j < 4; ++j) {
                        asm("v_fma_mix_f32 %0, %1, %2, %0 op_sel:[0,0,0] op_sel_hi:[1,0,0]"
                            : "+v"(ax) : "v"(v[j].x), "v"(one));
                        asm("v_fma_mix_f32 %0, %1, %2, %0 op_sel:[1,0,0] op_sel_hi:[1,0,0]"
                            : "+v"(ay) : "v"(v[j].x), "v"(one));
                        asm("v_fma_mix_f32 %0, %1, %2, %0 op_sel:[0,0,0] op_sel_hi:[1,0,0]"
                            : "+v"(az) : "v"(v[j].y), "v"(one));
                        asm("v_fma_mix_f32 %0, %1, %2, %0 op_sel:[1,0,0] op_sel_hi:[1,0,0]"
                            : "+v"(aw) : "v"(v[j].y), "v"(one));
                    }
                }
            }
            ax += __shfl_xor(ax, 32);
            ay += __shfl_xor(ay, 32);
            az += __shfl_xor(az, 32);
            aw += __shfl_xor(aw, 32);
            int deg = end - beg;
            float inv = (deg > 0) ? 1.0f / (float)deg : 0.0f;
            if (lane < 32) {
                half4v h;
                h[0] = (_Float16)(ax * inv);
                h[1] = (_Float16)(ay * inv);
                h[2] = (_Float16)(az * inv);
                h[3] = (_Float16)(aw * inv);
                int r = wave * 16 + k;     // agg tile row 0..63
                *(half4v*)((char*)a_lds + (r >> 2) * 1040 + (r & 3) * 256
                           + co) = h;
            }
        }
    }

    floatx16 acc[2];
#pragma unroll
    for (int r2 = 0; r2 < 2; ++r2)
#pragma unroll
        for (int r = 0; r < 16; ++r) acc[r2][r] = 0.0f;

    __syncthreads();                   // drains vmcnt (async LDS) + lgkmcnt

    // ---- 3. main loop: pure LDS + MFMA (32 MFMAs/wave) ----
#pragma unroll
    for (int ph = 0; ph < 2; ++ph)
#pragma unroll
        for (int ks = 0; ks < 8; ++ks)
#pragma unroll
            for (int r2 = 0; r2 < 2; ++r2) {
                int r = ph * 64 + r2 * 32 + l31;      // tile row 0..127
                int abyte = (r >> 2) * 1040 + (r & 3) * 256
                            + ks * 32 + lhi * 16;
                half8 af = *(const half8*)((const char*)a_lds + abyte);
                acc[r2] = __builtin_amdgcn_mfma_f32_32x32x16_f16(
                    af, breg[ph][ks], acc[r2], 0, 0, 0);
            }

    // ---- 4. epilogue ----
    {
        int col = wave * 32 + l31;
        float bv = bias[col];
#pragma unroll
        for (int r2 = 0; r2 < 2; ++r2)
#pragma unroll
            for (int r = 0; r < 16; ++r) {
                int rowin = (r & 3) + 8 * (r >> 2) + 4 * lhi;
                int grow = n0 + r2 * 32 + rowin;
                if (grow < N) {
                    float v = acc[r2][r] + bv;
                    if (GELU) v = gelu_fast(v);
                    out[(size_t)grow * 128 + col] = (OutT)v;
                }
            }
    }
}

// ---------------------------------------------------------------------------
extern "C" void kernel_launch(void* const* d_in, const int* in_sizes, int n_in,
                              void* d_out, int out_size, void* d_ws, size_t ws_size,
                              hipStream_t stream) {
    const float* embs = (const float*)d_in[0];
    const int*   ei0  = (const int*)d_in[1];
    const int*   ei1  = (const int*)d_in[2];
    const float* w_l0 = (const float*)d_in[3];
    const float* w_r0 = (const float*)d_in[4];
    const float* b0   = (const float*)d_in[5];
    const float* w_l1 = (const float*)d_in[6];
    const float* w_r1 = (const float*)d_in[7];
    const float* b1   = (const float*)d_in[8];
    float* out = (float*)d_out;

    const int N = in_sizes[0] / D;
    const int E = in_sizes[1] / 2;
    const int NBK = (N + BW - 1) >> SH;      // fine buckets per graph (196)
    const int NBIN = 2 * NBK;                // must be <= 512

    // ws: x_h[ND] h_h[ND] agg_h[ND] Bswz0 Bswz1 (halfs) |
    //     rp0[N+1] rp1[N+1] es0[E] es1[E] ccnt[NBIN*16] gbase[NBIN] gcur[NBIN*16]
    // stage0/stage1 alias agg_h (dead outside CSR build; 2E*4 <= N*D*2 bytes).
    _Float16* x_h   = (_Float16*)d_ws;
    _Float16* h_h   = x_h + (size_t)N * D;
    _Float16* agg_h = h_h + (size_t)N * D;   // now only CSR staging scratch
    _Float16* Bswz0 = agg_h + (size_t)N * D;
    _Float16* Bswz1 = Bswz0 + 64 * 512;
    int* rp0   = (int*)(Bswz1 + 64 * 512);
    int* rp1   = rp0 + (N + 1);
    int* es0   = rp1 + (N + 1);
    int* es1   = es0 + E;
    int* ccnt  = es1 + E;
    int* gbase = ccnt + NBIN * 16;
    int* gcur  = gbase + NBIN;
    int* stage0 = (int*)agg_h;
    int* stage1 = stage0 + E;

    const int cast_grid = ((size_t)N * D / 4 + 255) / 256;
    const int bin_grid  = (2 * E + 256 * EPT - 1) / (256 * EPT);
    const int gemm_grid = (N + 63) / 64;

    cast_half<<<cast_grid, 256, 0, stream>>>(embs, x_h, N * D);
    prep_bswz2<<<256, 256, 0, stream>>>(w_l0, w_r0, w_l1, w_r1, Bswz0, Bswz1);

    // ---- CSR build, both graphs ----
    hipMemsetAsync(ccnt, 0, (size_t)NBIN * 16 * sizeof(int), stream);
    hist_coarse<<<bin_grid, 256, 0, stream>>>(ei0, ei1, E, NBK, ccnt);
    scan_coarse<<<1, 256, 0, stream>>>(ccnt, NBK, E, N, gbase, gcur, rp0, rp1);
    bin_pass1<<<bin_grid, 256, 0, stream>>>(ei0, ei1, E, NBK, gcur,
                                            stage0, stage1);
    bin_pass2<<<NBIN, 256, 0, stream>>>(gbase, stage0, stage1,
                                        rp0, rp1, es0, es1, N, NBK, E);

    // ---- layer 0: fused gather+linear ----
    fused_sage<true, _Float16><<<gemm_grid, 256, 0, stream>>>(
        x_h, rp0, es0, Bswz0, b0, h_h, N);

    // ---- layer 1: fused gather+linear ----
    fused_sage<false, float><<<gemm_grid, 256, 0, stream>>>(
        h_h, rp1, es1, Bswz1, b1, out, N);
}

// Round 7
// 384.989 us; speedup vs baseline: 1.0158x; 1.0158x over previous
//
#include <hip/hip_runtime.h>
#include <hip/hip_fp16.h>
#include <math.h>

#define D 128
#define SH 9               // fine bucket shift: 512 dsts per bucket
#define BW (1 << SH)
#define EPT 16             // edges per thread in binning kernels

typedef _Float16 half4v __attribute__((ext_vector_type(4)));
typedef _Float16 half8  __attribute__((ext_vector_type(8)));
typedef float    floatx16 __attribute__((ext_vector_type(16)));

typedef __attribute__((address_space(3))) uint32_t lds_u32_t;
typedef const __attribute__((address_space(1))) uint32_t g_u32_t;

// ---------------------------------------------------------------------------
// Cast fp32 -> fp16 (4 elems/thread).
// ---------------------------------------------------------------------------
__global__ __launch_bounds__(256) void cast_half(
        const float* __restrict__ x, _Float16* __restrict__ y, int n) {
    int i = blockIdx.x * 256 + threadIdx.x;
    int idx = i * 4;
    if (idx >= n) return;
    float4 v = *(const float4*)(x + idx);
    half4v h;
    h[0] = (_Float16)v.x; h[1] = (_Float16)v.y;
    h[2] = (_Float16)v.z; h[3] = (_Float16)v.w;
    *(half4v*)(y + idx) = h;
}

// ---------------------------------------------------------------------------
// Build B fragments pre-swizzled for v_mfma_f32_32x32x16_f16, BOTH layers
// in one launch. WT[k][c] = (k<128) ? w_l[c][k] : w_r[c][k-128].
// Fragment f = ks*4+cb, lane l, elem j:
//   value = WT[ks*16 + (l>>5)*8 + j][cb*32 + (l&31)] at B[f*512 + l*8 + j].
// ---------------------------------------------------------------------------
__global__ __launch_bounds__(256) void prep_bswz2(
        const float* __restrict__ wl0, const float* __restrict__ wr0,
        const float* __restrict__ wl1, const float* __restrict__ wr1,
        _Float16* __restrict__ B0, _Float16* __restrict__ B1) {
    int gid = blockIdx.x * 256 + threadIdx.x;   // 2 * 32768
    if (gid >= 2 * 64 * 512) return;
    int layer = gid >> 15;
    int idx = gid & 32767;
    const float* wl = layer ? wl1 : wl0;
    const float* wr = layer ? wr1 : wr0;
    _Float16* B = layer ? B1 : B0;
    int j = idx & 7;
    int lane = (idx >> 3) & 63;
    int f = idx >> 9;
    int ks = f >> 2, cb = f & 3;
    int k = ks * 16 + (lane >> 5) * 8 + j;
    int c = cb * 32 + (lane & 31);
    float v = (k < 128) ? wl[c * 128 + k] : wr[c * 128 + (k - 128)];
    B[idx] = (_Float16)v;
}

// ---------------------------------------------------------------------------
// Coarse histogram: per (graph, fine-bucket) edge counts. LDS hist per block,
// one global atomic per nonzero bin per block (line-padded ccnt[b*16]).
// ---------------------------------------------------------------------------
__global__ __launch_bounds__(256) void hist_coarse(
        const int* __restrict__ ei0, const int* __restrict__ ei1,
        int E, int NBK, int* __restrict__ ccnt) {
    __shared__ int h[512];
    int NBIN = 2 * NBK;
    int t = threadIdx.x;
    h[t] = 0; h[t + 256] = 0;
    __syncthreads();
    int t0 = blockIdx.x * (256 * EPT) + t;
#pragma unroll
    for (int k = 0; k < EPT; ++k) {
        int idx = t0 + k * 256;
        if (idx < 2 * E) {
            int g = idx >= E;
            int e = idx - g * E;
            int dst = (g ? ei1 : ei0)[E + e];
            atomicAdd(&h[g * NBK + (dst >> SH)], 1);
        }
    }
    __syncthreads();
    for (int b = t; b < NBIN; b += 256)
        if (h[b]) atomicAdd(&ccnt[b * 16], h[b]);
}

// ---------------------------------------------------------------------------
// Coarse scan: one block; per-graph exclusive prefix over NBK bin counts.
// Writes gbase[b] (bucket start in stage/es space) and inits gcur[b*16].
// Also writes rp0[N]=rp1[N]=E.
// ---------------------------------------------------------------------------
__global__ __launch_bounds__(256) void scan_coarse(
        const int* __restrict__ ccnt, int NBK, int E, int N,
        int* __restrict__ gbase, int* __restrict__ gcur,
        int* __restrict__ rp0, int* __restrict__ rp1) {
    __shared__ int part[256];
    int t = threadIdx.x;
    for (int g = 0; g < 2; ++g) {
        int v = (t < NBK) ? ccnt[(g * NBK + t) * 16] : 0;
        part[t] = v;
        __syncthreads();
        for (int off = 1; off < 256; off <<= 1) {
            int u = (t >= off) ? part[t - off] : 0;
            __syncthreads();
            part[t] += u;
            __syncthreads();
        }
        if (t < NBK) {
            int ex = (t == 0) ? 0 : part[t - 1];
            int b = g * NBK + t;
            gbase[b] = ex;
            gcur[b * 16] = ex;
        }
        __syncthreads();
    }
    if (t == 0) { rp0[N] = E; rp1[N] = E; }
}

// ---------------------------------------------------------------------------
// Multisplit pass 1: bin edges into fine buckets. 4096 edges/block.
// LDS histogram -> one global reserve atomic per (block,bin) -> LDS-rank
// scatter of packed (src | dstlow<<17) into the per-graph stage array.
// ---------------------------------------------------------------------------
__global__ __launch_bounds__(256) void bin_pass1(
        const int* __restrict__ ei0, const int* __restrict__ ei1,
        int E, int NBK, int* __restrict__ gcur,
        int* __restrict__ stage0, int* __restrict__ stage1) {
    __shared__ int cnt[512];
    __shared__ int base[512];
    int NBIN = 2 * NBK;
    int t = threadIdx.x;
    cnt[t] = 0; cnt[t + 256] = 0;
    __syncthreads();
    int t0 = blockIdx.x * (256 * EPT) + t;
    int pk[EPT];
    int bn[EPT];
#pragma unroll
    for (int k = 0; k < EPT; ++k) {
        int idx = t0 + k * 256;
        bn[k] = -1;
        if (idx < 2 * E) {
            int g = idx >= E;
            int e = idx - g * E;
            const int* ei = g ? ei1 : ei0;
            int src = ei[e];
            int dst = ei[E + e];
            pk[k] = src | ((dst & (BW - 1)) << 17);
            bn[k] = g * NBK + (dst >> SH);
            atomicAdd(&cnt[bn[k]], 1);
        }
    }
    __syncthreads();
    for (int b = t; b < NBIN; b += 256) {
        int c = cnt[b];
        base[b] = c ? atomicAdd(&gcur[b * 16], c) : 0;
        cnt[b] = 0;  // reuse as rank counter
    }
    __syncthreads();
#pragma unroll
    for (int k = 0; k < EPT; ++k) {
        if (bn[k] >= 0) {
            int b = bn[k];
            int r = atomicAdd(&cnt[b], 1);
            int* stage = (b >= NBK) ? stage1 : stage0;
            stage[base[b] + r] = pk[k];
        }
    }
}

// ---------------------------------------------------------------------------
// Multisplit pass 2: one block per fine bucket (2*NBK blocks).
// Counts its 512 dsts in LDS, in-block scan -> writes row_ptr slice and LDS
// cursors, then scatters srcs into final CSR slots. All es writes for this
// ~32 KB region come from ONE block -> L2 merges to full lines.
// ---------------------------------------------------------------------------
__global__ __launch_bounds__(256) void bin_pass2(
        const int* __restrict__ gbase,
        const int* __restrict__ stage0, const int* __restrict__ stage1,
        int* __restrict__ rp0, int* __restrict__ rp1,
        int* __restrict__ es0, int* __restrict__ es1,
        int N, int NBK, int E) {
    __shared__ int cnt[BW];
    __shared__ int part[256];
    int b = blockIdx.x;
    int g = b >= NBK;
    int bk = b - g * NBK;
    const int* stage = g ? stage1 : stage0;
    int* rp = g ? rp1 : rp0;
    int* es = g ? es1 : es0;
    int lo = bk << SH;
    int hi = min(lo + BW, N);
    int nd = hi - lo;
    int beg = gbase[b];
    int end = (bk == NBK - 1) ? E : gbase[b + 1];
    int t = threadIdx.x;
    cnt[t] = 0; cnt[t + 256] = 0;
    __syncthreads();
    for (int i = beg + t; i < end; i += 256)
        atomicAdd(&cnt[(unsigned)stage[i] >> 17], 1);
    __syncthreads();
    int c0 = cnt[t * 2], c1 = cnt[t * 2 + 1];
    part[t] = c0 + c1;
    __syncthreads();
    for (int off = 1; off < 256; off <<= 1) {
        int u = (t >= off) ? part[t - off] : 0;
        __syncthreads();
        part[t] += u;
        __syncthreads();
    }
    int ex = (t == 0) ? 0 : part[t - 1];
    int base0 = beg + ex;
    if (t * 2 < nd)     rp[lo + t * 2]     = base0;
    if (t * 2 + 1 < nd) rp[lo + t * 2 + 1] = base0 + c0;
    __syncthreads();               // all reads of cnt done (scan barriers passed)
    cnt[t * 2] = base0;
    cnt[t * 2 + 1] = base0 + c0;
    __syncthreads();
    int i = beg + t;
    for (; i + 768 < end; i += 1024) {
        unsigned p0 = (unsigned)stage[i];
        unsigned p1 = (unsigned)stage[i + 256];
        unsigned p2 = (unsigned)stage[i + 512];
        unsigned p3 = (unsigned)stage[i + 768];
        int q0 = atomicAdd(&cnt[p0 >> 17], 1);
        int q1 = atomicAdd(&cnt[p1 >> 17], 1);
        int q2 = atomicAdd(&cnt[p2 >> 17], 1);
        int q3 = atomicAdd(&cnt[p3 >> 17], 1);
        es[q0] = p0 & 0x1FFFF;
        es[q1] = p1 & 0x1FFFF;
        es[q2] = p2 & 0x1FFFF;
        es[q3] = p3 & 0x1FFFF;
    }
    for (; i < end; i += 256) {
        unsigned p = (unsigned)stage[i];
        int q = atomicAdd(&cnt[p >> 17], 1);
        es[q] = p & 0x1FFFF;
    }
}

// ---------------------------------------------------------------------------
// Fast exact-GELU: erf via Abramowitz-Stegun 7.1.26 (|eps| <= 1.5e-7).
// ---------------------------------------------------------------------------
__device__ __forceinline__ float gelu_fast(float v) {
    float z = v * 0.70710678118654752f;
    float s = fabsf(z);
    float t = __builtin_amdgcn_rcpf(fmaf(0.3275911f, s, 1.0f));
    float poly = t * fmaf(t, fmaf(t, fmaf(t, fmaf(t, 1.061405429f,
                      -1.453152027f), 1.421413741f), -0.284496736f),
                      0.254829592f);
    float e = __builtin_amdgcn_exp2f(-1.4426950408889634f * s * s);
    float erfv = copysignf(fmaf(-poly, e, 1.0f), z);
    return 0.5f * v * (1.0f + erfv);
}

#define FMA_MIX_LO(acc, src) \
    asm("v_fma_mix_f32 %0, %1, %2, %0 op_sel:[0,0,0] op_sel_hi:[1,0,0]" \
        : "+v"(acc) : "v"(src), "v"(one))
#define FMA_MIX_HI(acc, src) \
    asm("v_fma_mix_f32 %0, %1, %2, %0 op_sel:[1,0,0] op_sel_hi:[1,0,0]" \
        : "+v"(acc) : "v"(src), "v"(one))

// ---------------------------------------------------------------------------
// FUSED gather-mean + SAGE linear, v7 (round 11).
// v6 post-mortem: fusion was occupancy-starved (33% vs agg's 71%) -> gather
// ran 2.29 TB/s vs 3.72. v7 restores latency cover inside the fusion:
//   - gather ILP x2: 16-lane x uint4 groups, 4 edges (4 KB) in flight/wave
//   - occupancy 3->4 blocks/CU: __launch_bounds__(256,4); fits the 128-reg
//     unified budget by holding only phase-0's 8 B-frags (32 VGPR, pinned)
//     across the gather; phase-1's load after the barrier, its L2 latency
//     hidden under phase-0's 16 MFMAs.
// ---------------------------------------------------------------------------
template <bool GELU, typename OutT>
__global__ __launch_bounds__(256, 4) void fused_sage(
        const _Float16* __restrict__ xsrc, const int* __restrict__ rp,
        const int* __restrict__ es, const _Float16* __restrict__ Bswz,
        const float* __restrict__ bias, OutT* __restrict__ out, int N) {
    __shared__ uint4 a_lds[32 * 65];   // 33280 B: 32 chunks of 4 rows + 16B pad

    const int tid = threadIdx.x;
    const int n0 = blockIdx.x * 64;
    const int wave = tid >> 6;
    const int lane = tid & 63;
    const int l31 = lane & 31;
    const int lhi = lane >> 5;

    // ---- 1a. x-row staging: chunks 16..31 hold x rows n0..n0+63 ----
    if (n0 + 64 <= N) {
#pragma unroll
        for (int i = 0; i < 4; ++i) {
            int c = 16 + wave * 4 + i;
            int r0 = n0 + 4 * (c & 15);
            const char* g = (const char*)xsrc + (size_t)r0 * 256 + lane * 16;
            uint32_t* l = (uint32_t*)((char*)a_lds + c * 1040);
            __builtin_amdgcn_global_load_lds((g_u32_t*)g, (lds_u32_t*)l,
                                             16, 0, 0);
        }
    } else {
#pragma unroll
        for (int i = 0; i < 4; ++i) {
            int c = 16 + wave * 4 + i;
            int grow = n0 + 4 * (c & 15) + (lane >> 4);
            uint4 v = make_uint4(0u, 0u, 0u, 0u);
            if (grow < N)
                v = *(const uint4*)((const char*)xsrc + (size_t)grow * 256
                                    + (lane & 15) * 16);
            *(uint4*)((char*)a_lds + c * 1040 + lane * 16) = v;
        }
    }

    // ---- 1b. B phase-0 fragments for col-block cb = wave, pinned ----
    half8 breg0[8];
#pragma unroll
    for (int ks = 0; ks < 8; ++ks)
        breg0[ks] = *(const half8*)(
            Bswz + ((ks * 4) + wave) * 512 + lane * 8);
#pragma unroll
    for (int ks = 0; ks < 8; ++ks)
        asm volatile("" : "+v"(breg0[ks]));

    // ---- 2. gather-mean: wave handles dst nodes n0+wave*16 .. +15 ----
    // 16-lane groups: g4 = edge slot (4 edges in flight), li = 16B dim slot.
    {
        int nb = n0 + wave * 16;
        int rpi = min(nb + lane, N);
        int rpv = (lane < 17) ? rp[rpi] : 0;
        const char* xb = (const char*)xsrc;
        int g4 = lane >> 4;
        int li = lane & 15;
        unsigned co = (unsigned)li * 16u;
        float one = 1.0f;
        for (int k = 0; k < 16; ++k) {
            int beg = __shfl(rpv, k);
            int end = __shfl(rpv, k + 1);
            float a0 = 0.f, a1 = 0.f, a2 = 0.f, a3 = 0.f;
            float a4 = 0.f, a5 = 0.f, a6 = 0.f, a7 = 0.f;
            for (int chunk = beg; chunk < end; chunk += 64) {
                int n = min(64, end - chunk);
                int iv = (lane < n) ? es[chunk + lane] : -1;
                for (int e = 0; e < n; e += 16) {
                    int s[4];
                    uint4 v[4];
#pragma unroll
                    for (int j = 0; j < 4; ++j) {
                        int ei_ = e + j * 4 + g4;
                        int sv = __shfl(iv, ei_);
                        s[j] = (ei_ < n) ? sv : -1;
                    }
#pragma unroll
                    for (int j = 0; j < 4; ++j) {
                        v[j] = make_uint4(0u, 0u, 0u, 0u);
                        if (s[j] >= 0)
                            v[j] = *(const uint4*)(xb + (unsigned)s[j] * 256u
                                                   + co);
                    }
#pragma unroll
                    for (int j = 0; j < 4; ++j) {
                        FMA_MIX_LO(a0, v[j].x); FMA_MIX_HI(a1, v[j].x);
                        FMA_MIX_LO(a2, v[j].y); FMA_MIX_HI(a3, v[j].y);
                        FMA_MIX_LO(a4, v[j].z); FMA_MIX_HI(a5, v[j].z);
                        FMA_MIX_LO(a6, v[j].w); FMA_MIX_HI(a7, v[j].w);
                    }
                }
            }
            a0 += __shfl_xor(a0, 16); a1 += __shfl_xor(a1, 16);
            a2 += __shfl_xor(a2, 16); a3 += __shfl_xor(a3, 16);
            a4 += __shfl_xor(a4, 16); a5 += __shfl_xor(a5, 16);
            a6 += __shfl_xor(a6, 16); a7 += __shfl_xor(a7, 16);
            a0 += __shfl_xor(a0, 32); a1 += __shfl_xor(a1, 32);
            a2 += __shfl_xor(a2, 32); a3 += __shfl_xor(a3, 32);
            a4 += __shfl_xor(a4, 32); a5 += __shfl_xor(a5, 32);
            a6 += __shfl_xor(a6, 32); a7 += __shfl_xor(a7, 32);
            int deg = end - beg;
            float inv = (deg > 0) ? 1.0f / (float)deg : 0.0f;
            if (g4 == 0) {
                half8 h;
                h[0] = (_Float16)(a0 * inv); h[1] = (_Float16)(a1 * inv);
                h[2] = (_Float16)(a2 * inv); h[3] = (_Float16)(a3 * inv);
                h[4] = (_Float16)(a4 * inv); h[5] = (_Float16)(a5 * inv);
                h[6] = (_Float16)(a6 * inv); h[7] = (_Float16)(a7 * inv);
                int r = wave * 16 + k;     // agg tile row 0..63
                *(half8*)((char*)a_lds + (r >> 2) * 1040 + (r & 3) * 256
                          + co) = h;
            }
        }
    }

    floatx16 acc[2];
#pragma unroll
    for (int r2 = 0; r2 < 2; ++r2)
#pragma unroll
        for (int r = 0; r < 16; ++r) acc[r2][r] = 0.0f;

    __syncthreads();                   // drains vmcnt (async LDS) + lgkmcnt

    // ---- 3a. phase-1 B fragments (issued now, latency under ph0 MFMAs) ----
    half8 breg1[8];
#pragma unroll
    for (int ks = 0; ks < 8; ++ks)
        breg1[ks] = *(const half8*)(
            Bswz + 16384 + ((ks * 4) + wave) * 512 + lane * 8);
#pragma unroll
    for (int ks = 0; ks < 8; ++ks)
        asm volatile("" : "+v"(breg1[ks]));

    // ---- 3b. MFMA: phase 0 (agg rows) then phase 1 (x rows) ----
#pragma unroll
    for (int ks = 0; ks < 8; ++ks)
#pragma unroll
        for (int r2 = 0; r2 < 2; ++r2) {
            int r = r2 * 32 + l31;
            int abyte = (r >> 2) * 1040 + (r & 3) * 256 + ks * 32 + lhi * 16;
            half8 af = *(const half8*)((const char*)a_lds + abyte);
            acc[r2] = __builtin_amdgcn_mfma_f32_32x32x16_f16(
                af, breg0[ks], acc[r2], 0, 0, 0);
        }
#pragma unroll
    for (int ks = 0; ks < 8; ++ks)
#pragma unroll
        for (int r2 = 0; r2 < 2; ++r2) {
            int r = 64 + r2 * 32 + l31;
            int abyte = (r >> 2) * 1040 + (r & 3) * 256 + ks * 32 + lhi * 16;
            half8 af = *(const half8*)((const char*)a_lds + abyte);
            acc[r2] = __builtin_amdgcn_mfma_f32_32x32x16_f16(
                af, breg1[ks], acc[r2], 0, 0, 0);
        }

    // ---- 4. epilogue ----
    {
        int col = wave * 32 + l31;
        float bv = bias[col];
#pragma unroll
        for (int r2 = 0; r2 < 2; ++r2)
#pragma unroll
            for (int r = 0; r < 16; ++r) {
                int rowin = (r & 3) + 8 * (r >> 2) + 4 * lhi;
                int grow = n0 + r2 * 32 + rowin;
                if (grow < N) {
                    float v = acc[r2][r] + bv;
                    if (GELU) v = gelu_fast(v);
                    out[(size_t)grow * 128 + col] = (OutT)v;
                }
            }
    }
}

// ---------------------------------------------------------------------------
extern "C" void kernel_launch(void* const* d_in, const int* in_sizes, int n_in,
                              void* d_out, int out_size, void* d_ws, size_t ws_size,
                              hipStream_t stream) {
    const float* embs = (const float*)d_in[0];
    const int*   ei0  = (const int*)d_in[1];
    const int*   ei1  = (const int*)d_in[2];
    const float* w_l0 = (const float*)d_in[3];
    const float* w_r0 = (const float*)d_in[4];
    const float* b0   = (const float*)d_in[5];
    const float* w_l1 = (const float*)d_in[6];
    const float* w_r1 = (const float*)d_in[7];
    const float* b1   = (const float*)d_in[8];
    float* out = (float*)d_out;

    const int N = in_sizes[0] / D;
    const int E = in_sizes[1] / 2;
    const int NBK = (N + BW - 1) >> SH;      // fine buckets per graph (196)
    const int NBIN = 2 * NBK;                // must be <= 512

    // ws: x_h[ND] h_h[ND] agg_h[ND] Bswz0 Bswz1 (halfs) |
    //     rp0[N+1] rp1[N+1] es0[E] es1[E] ccnt[NBIN*16] gbase[NBIN] gcur[NBIN*16]
    // stage0/stage1 alias agg_h (dead outside CSR build; 2E*4 <= N*D*2 bytes).
    _Float16* x_h   = (_Float16*)d_ws;
    _Float16* h_h   = x_h + (size_t)N * D;
    _Float16* agg_h = h_h + (size_t)N * D;   // CSR staging scratch only
    _Float16* Bswz0 = agg_h + (size_t)N * D;
    _Float16* Bswz1 = Bswz0 + 64 * 512;
    int* rp0   = (int*)(Bswz1 + 64 * 512);
    int* rp1   = rp0 + (N + 1);
    int* es0   = rp1 + (N + 1);
    int* es1   = es0 + E;
    int* ccnt  = es1 + E;
    int* gbase = ccnt + NBIN * 16;
    int* gcur  = gbase + NBIN;
    int* stage0 = (int*)agg_h;
    int* stage1 = stage0 + E;

    const int cast_grid = ((size_t)N * D / 4 + 255) / 256;
    const int bin_grid  = (2 * E + 256 * EPT - 1) / (256 * EPT);
    const int gemm_grid = (N + 63) / 64;

    cast_half<<<cast_grid, 256, 0, stream>>>(embs, x_h, N * D);
    prep_bswz2<<<256, 256, 0, stream>>>(w_l0, w_r0, w_l1, w_r1, Bswz0, Bswz1);

    // ---- CSR build, both graphs ----
    hipMemsetAsync(ccnt, 0, (size_t)NBIN * 16 * sizeof(int), stream);
    hist_coarse<<<bin_grid, 256, 0, stream>>>(ei0, ei1, E, NBK, ccnt);
    scan_coarse<<<1, 256, 0, stream>>>(ccnt, NBK, E, N, gbase, gcur, rp0, rp1);
    bin_pass1<<<bin_grid, 256, 0, stream>>>(ei0, ei1, E, NBK, gcur,
                                            stage0, stage1);
    bin_pass2<<<NBIN, 256, 0, stream>>>(gbase, stage0, stage1,
                                        rp0, rp1, es0, es1, N, NBK, E);

    // ---- layer 0: fused gather+linear ----
    fused_sage<true, _Float16><<<gemm_grid, 256, 0, stream>>>(
        x_h, rp0, es0, Bswz0, b0, h_h, N);

    // ---- layer 1: fused gather+linear ----
    fused_sage<false, float><<<gemm_grid, 256, 0, stream>>>(
        h_h, rp1, es1, Bswz1, b1, out, N);
}